// Round 3
// baseline (1032.394 us; speedup 1.0000x reference)
//
#include <hip/hip_runtime.h>
#include <hip/hip_bf16.h>
#include <cstdint>

// Problem constants
#define B_ROWS 16384
#define DIN    8192
#define NE_    4      // codebook entries
#define NEXP   8
#define HDEC   256
#define NCOL   40     // 8 gate cols + 32 (e,lat) cols
#define NWAVE  8
#define KS     (DIN / NWAVE)   // 1024 per wave
#define RPB    64              // rows per block

// ---------------- helpers ----------------
__device__ __forceinline__ float mishf(float x) {
    float sp = (x > 20.f) ? x : log1pf(expf(x));
    return x * tanhf(sp);
}
__device__ __forceinline__ double mishd(double x) {
    double sp = (x > 30.0) ? x : log1p(exp(x));
    return x * tanh(sp);
}
__device__ __forceinline__ void ln4d(const double* a, double* o) {
    double m  = (a[0] + a[1] + a[2] + a[3]) * 0.25;
    double d0 = a[0] - m, d1 = a[1] - m, d2 = a[2] - m, d3 = a[3] - m;
    double v  = (d0*d0 + d1*d1 + d2*d2 + d3*d3) * 0.25;
    double r  = 1.0 / sqrt(v + 1e-5);
    o[0] = d0*r; o[1] = d1*r; o[2] = d2*r; o[3] = d3*r;
}
__device__ __forceinline__ const float* uniform_ptr(const float* p) {
    uint64_t v  = (uint64_t)(uintptr_t)p;
    uint32_t lo = __builtin_amdgcn_readfirstlane((uint32_t)v);
    uint32_t hi = __builtin_amdgcn_readfirstlane((uint32_t)(v >> 32));
    return (const float*)(uintptr_t)(((uint64_t)hi << 32) | lo);
}

// ---------------------------------------------------------------------------
// Sentinel kernel: fires only if in_sizes don't match expectations.
// ---------------------------------------------------------------------------
__global__ __launch_bounds__(256) void sentinel_k(float* __restrict__ out, int n, float v) {
    int i = blockIdx.x * 256 + threadIdx.x;
    if (i < n) out[i] = v;
}

// ---------------------------------------------------------------------------
// Kernel 1: pack W40[k][j]: j<8 -> enc_gate_w[k][j]; else enc_w1[e][k][h]
// ---------------------------------------------------------------------------
__global__ __launch_bounds__(256) void prep_w40(const float* __restrict__ gw,
                                                const float* __restrict__ w1,
                                                float* __restrict__ w40) {
    int idx = blockIdx.x * 256 + threadIdx.x;   // exactly 8192*40 threads
    int k = idx / NCOL, j = idx - k * NCOL;
    float v;
    if (j < 8) {
        v = gw[k * 8 + j];
    } else {
        int e = (j - 8) >> 2, h = (j - 8) & 3;
        v = w1[((size_t)e * DIN + k) * 4 + h];
    }
    w40[idx] = v;
}

// ---------------------------------------------------------------------------
// Kernel 2: decoder expert outputs outE[c][e][8] (one block per (c,e))
// ---------------------------------------------------------------------------
__device__ __forceinline__ float blk_sum256(float v, volatile float* red) {
    #pragma unroll
    for (int off = 32; off > 0; off >>= 1) v += __shfl_down(v, off, 64);
    int lane = threadIdx.x & 63, w = threadIdx.x >> 6;
    if (lane == 0) red[w] = v;
    __syncthreads();
    float s = red[0] + red[1] + red[2] + red[3];
    __syncthreads();
    return s;
}

__global__ __launch_bounds__(256) void dec_expert(
    const float* __restrict__ w1, const float* __restrict__ b1,
    const float* __restrict__ w2, const float* __restrict__ b2,
    const float* __restrict__ w3, const float* __restrict__ b3,
    const float* __restrict__ w4, const float* __restrict__ b4,
    float* __restrict__ outE) {
    __shared__ float h[HDEC];
    __shared__ float red[4];
    int c = blockIdx.x >> 3, e = blockIdx.x & 7, t = threadIdx.x;

    // layer 1: h1 = LN(mish(w1[e,c,:] + b1[e]))
    float a   = mishf(w1[((size_t)e * NE_ + c) * HDEC + t] + b1[e * HDEC + t]);
    float m   = blk_sum256(a, red) * (1.f / HDEC);
    float d   = a - m;
    float var = blk_sum256(d * d, red) * (1.f / HDEC);
    h[t] = d * rsqrtf(var + 1e-5f);
    __syncthreads();

    // layer 2: h2 = LN(mish(h1 @ w2[e] + b2[e]))
    float s = b2[e * HDEC + t];
    for (int i = 0; i < HDEC; ++i) s += h[i] * w2[((size_t)e * HDEC + i) * HDEC + t];
    __syncthreads();
    a   = mishf(s);
    m   = blk_sum256(a, red) * (1.f / HDEC);
    d   = a - m;
    var = blk_sum256(d * d, red) * (1.f / HDEC);
    h[t] = d * rsqrtf(var + 1e-5f);
    __syncthreads();

    // layer 3: h3 = mish(h2 @ w3[e] + b3[e])   (no LN)
    s = b3[e * HDEC + t];
    for (int i = 0; i < HDEC; ++i) s += h[i] * w3[((size_t)e * HDEC + i) * HDEC + t];
    __syncthreads();
    float h3 = mishf(s);

    // out8: outE[c][e][j] = sum_t h3[t]*w4[e,t,j] + b4[e,j]
    for (int j = 0; j < 8; ++j) {
        float oj = blk_sum256(h3 * w4[((size_t)e * HDEC + t) * 8 + j], red);
        if (t == 0) outE[((size_t)c * 8 + e) * 8 + j] = oj + b4[e * 8 + j];
    }
}

// ---------------------------------------------------------------------------
// Kernel 3: fused skinny GEMM (f64 chunked accumulation) + per-row f64 tail
// 256 blocks x 512 threads; wave wv owns K-slice [wv*1024, +1024) for 64 rows
// ---------------------------------------------------------------------------
__global__ __launch_bounds__(512) void fused_main(
    const float* __restrict__ x,   const float* __restrict__ w40,
    const float* __restrict__ outE,
    const float* __restrict__ gu,  const float* __restrict__ cb,
    const float* __restrict__ egb, const float* __restrict__ eb1,
    const float* __restrict__ ew2, const float* __restrict__ eb2,
    const float* __restrict__ ew3, const float* __restrict__ eb3,
    const float* __restrict__ ew4, const float* __restrict__ eb4,
    const float* __restrict__ dgw, const float* __restrict__ dgb,
    float* __restrict__ out)
{
    __shared__ double plane[RPB][NCOL];   // 20,480 B
    const int t  = threadIdx.x;
    const int wv = t >> 6, r = t & 63;
    const int row = blockIdx.x * RPB + r;

    const float* __restrict__ xr = x + (size_t)row * DIN + wv * KS;
    const float* __restrict__ wk = uniform_ptr(w40 + (size_t)wv * KS * NCOL);

    double acc[NCOL];
    #pragma unroll
    for (int j = 0; j < NCOL; ++j) acc[j] = 0.0;

    for (int c = 0; c < KS / 32; ++c) {          // 32 chunks of 32 k
        float xv[32];
        #pragma unroll
        for (int q = 0; q < 8; ++q)
            *reinterpret_cast<float4*>(&xv[q * 4]) =
                *reinterpret_cast<const float4*>(xr + c * 32 + q * 4);
        float f[NCOL];
        #pragma unroll
        for (int j = 0; j < NCOL; ++j) f[j] = 0.f;
        #pragma unroll
        for (int kk = 0; kk < 32; ++kk) {
            const float* __restrict__ wr = wk + (c * 32 + kk) * NCOL;  // wave-uniform
            const float xs = xv[kk];
            #pragma unroll
            for (int j = 0; j < NCOL; ++j) f[j] = fmaf(xs, wr[j], f[j]);
        }
        #pragma unroll
        for (int j = 0; j < NCOL; ++j) acc[j] += (double)f[j];
    }

    // cross-wave reduction (deterministic order wv = 0..7)
    for (int src = 1; src < NWAVE; ++src) {
        if (wv == src) {
            #pragma unroll
            for (int j = 0; j < NCOL; ++j) plane[r][j] = acc[j];
        }
        __syncthreads();
        if (wv == 0) {
            #pragma unroll
            for (int j = 0; j < NCOL; ++j) acc[j] += plane[r][j];
        }
        __syncthreads();
    }
    if (wv != 0) return;

    // -------- per-row tail, all f64 --------
    // encoder gate softmax
    double gv[8], mx = -1e300, gs = 0.0;
    #pragma unroll
    for (int e = 0; e < 8; ++e) { gv[e] = acc[e] + (double)egb[e]; mx = fmax(mx, gv[e]); }
    #pragma unroll
    for (int e = 0; e < 8; ++e) { gv[e] = exp(gv[e] - mx); gs += gv[e]; }
    double inv = 1.0 / gs;

    double est[4] = {0, 0, 0, 0};
    #pragma unroll
    for (int e = 0; e < 8; ++e) {
        double a[4], l1[4], p2[4], l2[4], h3[4];
        #pragma unroll
        for (int hh = 0; hh < 4; ++hh)
            a[hh] = mishd(acc[8 + e * 4 + hh] + (double)eb1[e * 4 + hh]);
        ln4d(a, l1);
        #pragma unroll
        for (int hh = 0; hh < 4; ++hh) {
            double s = (double)eb2[e * 4 + hh];
            #pragma unroll
            for (int i = 0; i < 4; ++i) s += l1[i] * (double)ew2[(e * 4 + i) * 4 + hh];
            p2[hh] = mishd(s);
        }
        ln4d(p2, l2);
        #pragma unroll
        for (int hh = 0; hh < 4; ++hh) {
            double s = (double)eb3[e * 4 + hh];
            #pragma unroll
            for (int i = 0; i < 4; ++i) s += l2[i] * (double)ew3[(e * 4 + i) * 4 + hh];
            h3[hh] = mishd(s);
        }
        double g = gv[e] * inv;
        #pragma unroll
        for (int hh = 0; hh < 4; ++hh) {
            double s = (double)eb4[e * 4 + hh];
            #pragma unroll
            for (int i = 0; i < 4; ++i) s += h3[i] * (double)ew4[(e * 4 + i) * 4 + hh];
            est[hh] += g * s;
        }
    }

    // logits + gumbel + first-max argmax (clip bounds match fp32 semantics)
    const double ulo = (double)1e-10f, uhi = (double)(1.0f - 1e-7f);
    double best = -1e300; int kb = 0;
    #pragma unroll
    for (int n = 0; n < 4; ++n) {
        double lg = 0.0;
        #pragma unroll
        for (int l = 0; l < 4; ++l) lg += est[l] * (double)cb[n * 4 + l];
        double u = (double)gu[(size_t)row * 4 + n];
        u = fmin(fmax(u, ulo), uhi);
        double z = lg - log(-log(u));   // TAU = 1
        if (z > best) { best = z; kb = n; }
    }

    // decoder gate softmax (depends only on codeword kb) + expert combine
    double g2[8], mx2 = -1e300, gs2 = 0.0;
    #pragma unroll
    for (int e = 0; e < 8; ++e) {
        g2[e] = (double)dgw[kb * 8 + e] + (double)dgb[e];
        mx2 = fmax(mx2, g2[e]);
    }
    #pragma unroll
    for (int e = 0; e < 8; ++e) { g2[e] = exp(g2[e] - mx2); gs2 += g2[e]; }
    double inv2 = 1.0 / gs2;

    // f32 OUTPUT (reference returns jnp.float32)
    float o[8];
    #pragma unroll
    for (int j = 0; j < 8; ++j) {
        double s = 0.0;
        #pragma unroll
        for (int e = 0; e < 8; ++e)
            s += g2[e] * (double)outE[((size_t)kb * 8 + e) * 8 + j];
        o[j] = (float)(s * inv2);
    }
    float* op = out + (size_t)row * 8;
    *reinterpret_cast<float4*>(op)     = make_float4(o[0], o[1], o[2], o[3]);
    *reinterpret_cast<float4*>(op + 4) = make_float4(o[4], o[5], o[6], o[7]);
}

// ---------------------------------------------------------------------------
extern "C" void kernel_launch(void* const* d_in, const int* in_sizes, int n_in,
                              void* d_out, int out_size, void* d_ws, size_t ws_size,
                              hipStream_t stream) {
    float* out = (float*)d_out;

    // ---- input-layout guard: distinct failure signature if assumptions wrong
    static const int expect[23] = {
        B_ROWS * DIN,            // x
        B_ROWS * NE_,            // gumbel_u
        NE_ * 4,                 // codebook
        DIN * NEXP,              // enc_gate_w
        NEXP,                    // enc_gate_b
        NEXP * DIN * 4,          // enc_w1
        NEXP * 4,                // enc_b1
        NEXP * 16,               // enc_w2
        NEXP * 4,                // enc_b2
        NEXP * 16,               // enc_w3
        NEXP * 4,                // enc_b3
        NEXP * 16,               // enc_w4
        NEXP * 4,                // enc_b4
        NE_ * NEXP,              // dec_gate_w
        NEXP,                    // dec_gate_b
        NEXP * NE_ * HDEC,       // dec_w1
        NEXP * HDEC,             // dec_b1
        NEXP * HDEC * HDEC,      // dec_w2
        NEXP * HDEC,             // dec_b2
        NEXP * HDEC * HDEC,      // dec_w3
        NEXP * HDEC,             // dec_b3
        NEXP * HDEC * 8,         // dec_w4
        NEXP * 8                 // dec_b4
    };
    bool ok = (n_in == 23) && (out_size == B_ROWS * 8) &&
              (ws_size >= (size_t)(DIN * NCOL + 512) * sizeof(float));
    if (ok) {
        for (int i = 0; i < 23; ++i) ok = ok && (in_sizes[i] == expect[i]);
    }
    if (!ok) {
        sentinel_k<<<(out_size + 255) / 256, 256, 0, stream>>>(out, out_size, 1.0e6f);
        return;
    }

    const float* x   = (const float*)d_in[0];
    const float* gu  = (const float*)d_in[1];
    const float* cb  = (const float*)d_in[2];
    const float* egw = (const float*)d_in[3];
    const float* egb = (const float*)d_in[4];
    const float* ew1 = (const float*)d_in[5];
    const float* eb1 = (const float*)d_in[6];
    const float* ew2 = (const float*)d_in[7];
    const float* eb2 = (const float*)d_in[8];
    const float* ew3 = (const float*)d_in[9];
    const float* eb3 = (const float*)d_in[10];
    const float* ew4 = (const float*)d_in[11];
    const float* eb4 = (const float*)d_in[12];
    const float* dgw = (const float*)d_in[13];
    const float* dgb = (const float*)d_in[14];
    const float* dw1 = (const float*)d_in[15];
    const float* db1 = (const float*)d_in[16];
    const float* dw2 = (const float*)d_in[17];
    const float* db2 = (const float*)d_in[18];
    const float* dw3 = (const float*)d_in[19];
    const float* db3 = (const float*)d_in[20];
    const float* dw4 = (const float*)d_in[21];
    const float* db4 = (const float*)d_in[22];

    float* w40  = (float*)d_ws;                     // 8192*40 floats = 1.31 MB
    float* outE = w40 + (size_t)DIN * NCOL;         // 4*8*8 = 256 floats

    prep_w40  <<<(DIN * NCOL) / 256, 256, 0, stream>>>(egw, ew1, w40);
    dec_expert<<<NE_ * NEXP, 256, 0, stream>>>(dw1, db1, dw2, db2, dw3, db3,
                                               dw4, db4, outE);
    fused_main<<<B_ROWS / RPB, 512, 0, stream>>>(x, w40, outE, gu, cb, egb, eb1,
                                                 ew2, eb2, ew3, eb3, ew4, eb4,
                                                 dgw, dgb, out);
}

// Round 4
// 844.558 us; speedup vs baseline: 1.2224x; 1.2224x over previous
//
#include <hip/hip_runtime.h>
#include <hip/hip_bf16.h>
#include <cstdint>

// Problem constants
#define B_ROWS 16384
#define DIN    8192
#define NE_    4      // codebook entries
#define NEXP   8
#define HDEC   256
#define NCOL   40     // 8 gate cols + 32 (e,lat) cols
#define ROWS_PB 16    // rows per block
#define CHUNK  256    // K per staged chunk
#define NCHUNK (DIN / CHUNK)   // 32
#define RPW 8         // rows per wave (row-group size)
#define CPW 5         // cols per wave

// ---------------- helpers ----------------
__device__ __forceinline__ float mishf(float x) {
    float sp = (x > 20.f) ? x : log1pf(expf(x));
    return x * tanhf(sp);
}
__device__ __forceinline__ double mishd(double x) {
    double sp = (x > 30.0) ? x : log1p(exp(x));
    return x * tanh(sp);
}
__device__ __forceinline__ void ln4d(const double* a, double* o) {
    double m  = (a[0] + a[1] + a[2] + a[3]) * 0.25;
    double d0 = a[0] - m, d1 = a[1] - m, d2 = a[2] - m, d3 = a[3] - m;
    double v  = (d0*d0 + d1*d1 + d2*d2 + d3*d3) * 0.25;
    double r  = 1.0 / sqrt(v + 1e-5);
    o[0] = d0*r; o[1] = d1*r; o[2] = d2*r; o[3] = d3*r;
}

// ---------------------------------------------------------------------------
// Sentinel kernel: fires only if in_sizes don't match expectations.
// ---------------------------------------------------------------------------
__global__ __launch_bounds__(256) void sentinel_k(float* __restrict__ out, int n, float v) {
    int i = blockIdx.x * 256 + threadIdx.x;
    if (i < n) out[i] = v;
}

// ---------------------------------------------------------------------------
// Kernel 1: pack TRANSPOSED w40T[j][k]: j<8 -> enc_gate_w[k][j];
//           j>=8 -> enc_w1[e][k][h], e=(j-8)>>2, h=(j-8)&3
// ---------------------------------------------------------------------------
__global__ __launch_bounds__(256) void prep_w40t(const float* __restrict__ gw,
                                                 const float* __restrict__ w1,
                                                 float* __restrict__ w40t) {
    int idx = blockIdx.x * 256 + threadIdx.x;   // 40*8192 threads
    int j = idx >> 13, k = idx & (DIN - 1);
    float v;
    if (j < 8) {
        v = gw[k * 8 + j];
    } else {
        int e = (j - 8) >> 2, h = (j - 8) & 3;
        v = w1[((size_t)e * DIN + k) * 4 + h];
    }
    w40t[idx] = v;   // coalesced write
}

// ---------------------------------------------------------------------------
// Kernel 2: decoder expert outputs outE[c][e][8] (one block per (c,e))
// ---------------------------------------------------------------------------
__device__ __forceinline__ float blk_sum256(float v, volatile float* red) {
    #pragma unroll
    for (int off = 32; off > 0; off >>= 1) v += __shfl_down(v, off, 64);
    int lane = threadIdx.x & 63, w = threadIdx.x >> 6;
    if (lane == 0) red[w] = v;
    __syncthreads();
    float s = red[0] + red[1] + red[2] + red[3];
    __syncthreads();
    return s;
}

__global__ __launch_bounds__(256) void dec_expert(
    const float* __restrict__ w1, const float* __restrict__ b1,
    const float* __restrict__ w2, const float* __restrict__ b2,
    const float* __restrict__ w3, const float* __restrict__ b3,
    const float* __restrict__ w4, const float* __restrict__ b4,
    float* __restrict__ outE) {
    __shared__ float h[HDEC];
    __shared__ float red[4];
    int c = blockIdx.x >> 3, e = blockIdx.x & 7, t = threadIdx.x;

    float a   = mishf(w1[((size_t)e * NE_ + c) * HDEC + t] + b1[e * HDEC + t]);
    float m   = blk_sum256(a, red) * (1.f / HDEC);
    float d   = a - m;
    float var = blk_sum256(d * d, red) * (1.f / HDEC);
    h[t] = d * rsqrtf(var + 1e-5f);
    __syncthreads();

    float s = b2[e * HDEC + t];
    for (int i = 0; i < HDEC; ++i) s += h[i] * w2[((size_t)e * HDEC + i) * HDEC + t];
    __syncthreads();
    a   = mishf(s);
    m   = blk_sum256(a, red) * (1.f / HDEC);
    d   = a - m;
    var = blk_sum256(d * d, red) * (1.f / HDEC);
    h[t] = d * rsqrtf(var + 1e-5f);
    __syncthreads();

    s = b3[e * HDEC + t];
    for (int i = 0; i < HDEC; ++i) s += h[i] * w3[((size_t)e * HDEC + i) * HDEC + t];
    __syncthreads();
    float h3 = mishf(s);

    for (int j = 0; j < 8; ++j) {
        float oj = blk_sum256(h3 * w4[((size_t)e * HDEC + t) * 8 + j], red);
        if (t == 0) outE[((size_t)c * 8 + e) * 8 + j] = oj + b4[e * 8 + j];
    }
}

// ---------------------------------------------------------------------------
// Kernel 3: LDS-staged skinny GEMM + f64 tail.
// 1024 blocks x 1024 threads (16 waves = 2 row-groups x 8 col-groups).
// Block covers 16 rows, all 40 cols, full K. K-chunk 256 double-buffered.
// ---------------------------------------------------------------------------
__global__ __launch_bounds__(1024, 4) void fused_main(
    const float* __restrict__ x,   const float* __restrict__ w40t,
    const float* __restrict__ outE,
    const float* __restrict__ gu,  const float* __restrict__ cb,
    const float* __restrict__ egb, const float* __restrict__ eb1,
    const float* __restrict__ ew2, const float* __restrict__ eb2,
    const float* __restrict__ ew3, const float* __restrict__ eb3,
    const float* __restrict__ ew4, const float* __restrict__ eb4,
    const float* __restrict__ dgw, const float* __restrict__ dgb,
    float* __restrict__ out)
{
    __shared__ float wlds[2][NCOL][CHUNK];   // 81920 B

    const int t    = threadIdx.x;
    const int lane = t & 63;
    const int wv   = t >> 6;
    const int rg   = wv >> 3;          // 0..1
    const int cg   = wv & 7;           // 0..7
    const int rowBase = blockIdx.x * ROWS_PB;
    const int row0 = rowBase + rg * RPW;
    const int j0   = cg * CPW;

    const float* __restrict__ xrow = x + (size_t)row0 * DIN;

    // staging map: float4 id f -> (col j = f>>6, k-offset kk = (f&63)*4)
    // per chunk: 40*256/4 = 2560 float4; threads handle f = t, t+1024, (+2048 if t<512)
    const bool st3 = (t < 512);

    float acc[RPW][CPW];
    #pragma unroll
    for (int r = 0; r < RPW; ++r)
        #pragma unroll
        for (int jj = 0; jj < CPW; ++jj) acc[r][jj] = 0.f;

    // ---- prologue: stage chunk 0 into buf 0
    {
        int f0 = t, f1 = t + 1024, f2 = t + 2048;
        float4 g0 = *(const float4*)(w40t + (size_t)(f0 >> 6) * DIN + ((f0 & 63) << 2));
        float4 g1 = *(const float4*)(w40t + (size_t)(f1 >> 6) * DIN + ((f1 & 63) << 2));
        float4 g2;
        if (st3) g2 = *(const float4*)(w40t + (size_t)(f2 >> 6) * DIN + ((f2 & 63) << 2));
        *(float4*)(&wlds[0][0][0] + (f0 >> 6) * CHUNK + ((f0 & 63) << 2)) = g0;
        *(float4*)(&wlds[0][0][0] + (f1 >> 6) * CHUNK + ((f1 & 63) << 2)) = g1;
        if (st3)
            *(float4*)(&wlds[0][0][0] + (f2 >> 6) * CHUNK + ((f2 & 63) << 2)) = g2;
    }
    __syncthreads();

    for (int c = 0; c < NCHUNK; ++c) {
        const int cur = c & 1;
        const int k0  = c * CHUNK;

        // issue next-chunk staging loads early (hide under compute)
        float4 g0, g1, g2;
        if (c + 1 < NCHUNK) {
            const float* wn = w40t + (k0 + CHUNK);
            int f0 = t, f1 = t + 1024, f2 = t + 2048;
            g0 = *(const float4*)(wn + (size_t)(f0 >> 6) * DIN + ((f0 & 63) << 2));
            g1 = *(const float4*)(wn + (size_t)(f1 >> 6) * DIN + ((f1 & 63) << 2));
            if (st3) g2 = *(const float4*)(wn + (size_t)(f2 >> 6) * DIN + ((f2 & 63) << 2));
        }

        // this wave's 5 col-fragments (each = its lane's 4 k-values)
        float4 wreg[CPW];
        #pragma unroll
        for (int jj = 0; jj < CPW; ++jj)
            wreg[jj] = *(const float4*)(&wlds[cur][j0 + jj][lane << 2]);

        // rows with 1-deep x prefetch
        float4 xv = *(const float4*)(xrow + k0 + (lane << 2));
        #pragma unroll
        for (int r = 0; r < RPW; ++r) {
            float4 xn;
            if (r + 1 < RPW)
                xn = *(const float4*)(xrow + (size_t)(r + 1) * DIN + k0 + (lane << 2));
            #pragma unroll
            for (int jj = 0; jj < CPW; ++jj) {
                float4 w = wreg[jj];
                acc[r][jj] += (xv.x * w.x + xv.y * w.y) + (xv.z * w.z + xv.w * w.w);
            }
            xv = xn;
        }

        __syncthreads();   // all waves done reading buf[cur^1] writes target
        if (c + 1 < NCHUNK) {
            float* wb = &wlds[cur ^ 1][0][0];
            int f0 = t, f1 = t + 1024, f2 = t + 2048;
            *(float4*)(wb + (f0 >> 6) * CHUNK + ((f0 & 63) << 2)) = g0;
            *(float4*)(wb + (f1 >> 6) * CHUNK + ((f1 & 63) << 2)) = g1;
            if (st3)
                *(float4*)(wb + (f2 >> 6) * CHUNK + ((f2 & 63) << 2)) = g2;
        }
        __syncthreads();   // next chunk's buffer ready
    }

    // ---- cross-lane f64 reduction into LDS y[16][40] (aliases wlds[0])
    double* ylds = reinterpret_cast<double*>(&wlds[0][0][0]);
    #pragma unroll
    for (int r = 0; r < RPW; ++r) {
        #pragma unroll
        for (int jj = 0; jj < CPW; ++jj) {
            double v = (double)acc[r][jj];
            #pragma unroll
            for (int off = 32; off > 0; off >>= 1) v += __shfl_xor(v, off, 64);
            if (lane == 0) ylds[(rg * RPW + r) * NCOL + (j0 + jj)] = v;
        }
    }
    __syncthreads();

    // ---- per-row f64 tail: lanes 0..15 of the block, one row each
    if (t < ROWS_PB) {
        const int row = rowBase + t;
        double y[NCOL];
        #pragma unroll
        for (int j = 0; j < NCOL; ++j) y[j] = ylds[t * NCOL + j];

        // encoder gate softmax
        double gv[8], mx = -1e300, gs = 0.0;
        #pragma unroll
        for (int e = 0; e < 8; ++e) { gv[e] = y[e] + (double)egb[e]; mx = fmax(mx, gv[e]); }
        #pragma unroll
        for (int e = 0; e < 8; ++e) { gv[e] = exp(gv[e] - mx); gs += gv[e]; }
        double inv = 1.0 / gs;

        double est[4] = {0, 0, 0, 0};
        #pragma unroll
        for (int e = 0; e < 8; ++e) {
            double a[4], l1[4], p2[4], l2[4], h3[4];
            #pragma unroll
            for (int hh = 0; hh < 4; ++hh)
                a[hh] = mishd(y[8 + e * 4 + hh] + (double)eb1[e * 4 + hh]);
            ln4d(a, l1);
            #pragma unroll
            for (int hh = 0; hh < 4; ++hh) {
                double s = (double)eb2[e * 4 + hh];
                #pragma unroll
                for (int i = 0; i < 4; ++i) s += l1[i] * (double)ew2[(e * 4 + i) * 4 + hh];
                p2[hh] = mishd(s);
            }
            ln4d(p2, l2);
            #pragma unroll
            for (int hh = 0; hh < 4; ++hh) {
                double s = (double)eb3[e * 4 + hh];
                #pragma unroll
                for (int i = 0; i < 4; ++i) s += l2[i] * (double)ew3[(e * 4 + i) * 4 + hh];
                h3[hh] = mishd(s);
            }
            double g = gv[e] * inv;
            #pragma unroll
            for (int hh = 0; hh < 4; ++hh) {
                double s = (double)eb4[e * 4 + hh];
                #pragma unroll
                for (int i = 0; i < 4; ++i) s += h3[i] * (double)ew4[(e * 4 + i) * 4 + hh];
                est[hh] += g * s;
            }
        }

        // logits + gumbel + first-max argmax
        const double ulo = (double)1e-10f, uhi = (double)(1.0f - 1e-7f);
        double best = -1e300; int kb = 0;
        #pragma unroll
        for (int n = 0; n < 4; ++n) {
            double lg = 0.0;
            #pragma unroll
            for (int l = 0; l < 4; ++l) lg += est[l] * (double)cb[n * 4 + l];
            double u = (double)gu[(size_t)row * 4 + n];
            u = fmin(fmax(u, ulo), uhi);
            double z = lg - log(-log(u));   // TAU = 1
            if (z > best) { best = z; kb = n; }
        }

        // decoder gate softmax + expert combine
        double g2[8], mx2 = -1e300, gs2 = 0.0;
        #pragma unroll
        for (int e = 0; e < 8; ++e) {
            g2[e] = (double)dgw[kb * 8 + e] + (double)dgb[e];
            mx2 = fmax(mx2, g2[e]);
        }
        #pragma unroll
        for (int e = 0; e < 8; ++e) { g2[e] = exp(g2[e] - mx2); gs2 += g2[e]; }
        double inv2 = 1.0 / gs2;

        float o[8];
        #pragma unroll
        for (int j = 0; j < 8; ++j) {
            double s = 0.0;
            #pragma unroll
            for (int e = 0; e < 8; ++e)
                s += g2[e] * (double)outE[((size_t)kb * 8 + e) * 8 + j];
            o[j] = (float)(s * inv2);
        }
        float* op = out + (size_t)row * 8;
        *reinterpret_cast<float4*>(op)     = make_float4(o[0], o[1], o[2], o[3]);
        *reinterpret_cast<float4*>(op + 4) = make_float4(o[4], o[5], o[6], o[7]);
    }
}

// ---------------------------------------------------------------------------
extern "C" void kernel_launch(void* const* d_in, const int* in_sizes, int n_in,
                              void* d_out, int out_size, void* d_ws, size_t ws_size,
                              hipStream_t stream) {
    float* out = (float*)d_out;

    static const int expect[23] = {
        B_ROWS * DIN, B_ROWS * NE_, NE_ * 4,
        DIN * NEXP, NEXP,
        NEXP * DIN * 4, NEXP * 4,
        NEXP * 16, NEXP * 4,
        NEXP * 16, NEXP * 4,
        NEXP * 16, NEXP * 4,
        NE_ * NEXP, NEXP,
        NEXP * NE_ * HDEC, NEXP * HDEC,
        NEXP * HDEC * HDEC, NEXP * HDEC,
        NEXP * HDEC * HDEC, NEXP * HDEC,
        NEXP * HDEC * 8, NEXP * 8
    };
    bool ok = (n_in == 23) && (out_size == B_ROWS * 8) &&
              (ws_size >= (size_t)(DIN * NCOL + 512) * sizeof(float));
    if (ok) {
        for (int i = 0; i < 23; ++i) ok = ok && (in_sizes[i] == expect[i]);
    }
    if (!ok) {
        sentinel_k<<<(out_size + 255) / 256, 256, 0, stream>>>(out, out_size, 1.0e6f);
        return;
    }

    const float* x   = (const float*)d_in[0];
    const float* gu  = (const float*)d_in[1];
    const float* cb  = (const float*)d_in[2];
    const float* egw = (const float*)d_in[3];
    const float* egb = (const float*)d_in[4];
    const float* ew1 = (const float*)d_in[5];
    const float* eb1 = (const float*)d_in[6];
    const float* ew2 = (const float*)d_in[7];
    const float* eb2 = (const float*)d_in[8];
    const float* ew3 = (const float*)d_in[9];
    const float* eb3 = (const float*)d_in[10];
    const float* ew4 = (const float*)d_in[11];
    const float* eb4 = (const float*)d_in[12];
    const float* dgw = (const float*)d_in[13];
    const float* dgb = (const float*)d_in[14];
    const float* dw1 = (const float*)d_in[15];
    const float* db1 = (const float*)d_in[16];
    const float* dw2 = (const float*)d_in[17];
    const float* db2 = (const float*)d_in[18];
    const float* dw3 = (const float*)d_in[19];
    const float* db3 = (const float*)d_in[20];
    const float* dw4 = (const float*)d_in[21];
    const float* db4 = (const float*)d_in[22];

    float* w40t = (float*)d_ws;                     // 40*8192 floats = 1.31 MB
    float* outE = w40t + (size_t)NCOL * DIN;        // 256 floats

    prep_w40t <<<(NCOL * DIN) / 256, 256, 0, stream>>>(egw, ew1, w40t);
    dec_expert<<<NE_ * NEXP, 256, 0, stream>>>(dw1, db1, dw2, db2, dw3, db3,
                                               dw4, db4, outE);
    fused_main<<<B_ROWS / ROWS_PB, 1024, 0, stream>>>(x, w40t, outE, gu, cb,
                                                      egb, eb1, ew2, eb2, ew3,
                                                      eb3, ew4, eb4, dgw, dgb,
                                                      out);
}